// Round 1
// 3961.531 us; speedup vs baseline: 1.7032x; 1.7032x over previous
//
#include <hip/hip_runtime.h>
#include <math.h>

#define NRAYS 262144
#define MAXIT 192
#define NEARV 0.2f
#define FARV  2.0f
#define EPSV  0.001f
#define KCHUNK 16
#define NROUNDS 12   // KCHUNK * NROUNDS == MAXIT

// ---------------------------------------------------------------------------
// SDF MLP evaluation — bit-identical arithmetic to the previously passing
// kernel (same fma order, scalar wave-uniform weight loads -> s_load).
// ---------------------------------------------------------------------------
__device__ __forceinline__ float sdf_eval(
    float px, float py, float pz,
    const float* __restrict__ W0, const float* __restrict__ b0,
    const float* __restrict__ W1, const float* __restrict__ b1,
    const float* __restrict__ W2, float b2_0)
{
    float h1[64];
    #pragma unroll
    for (int j = 0; j < 64; ++j) h1[j] = 0.f;

    for (int k = 0; k < 64; ++k) {
        float z = px * W0[k] + py * W0[64 + k] + pz * W0[128 + k];
        z += b0[k];
        const float a = fmaxf(z, 0.f);
        #pragma unroll
        for (int j = 0; j < 64; ++j) h1[j] = fmaf(a, W1[k * 64 + j], h1[j]);
    }

    float d = 0.f;
    #pragma unroll
    for (int j = 0; j < 64; ++j)
        d = fmaf(fmaxf(h1[j] + b1[j], 0.f), W2[j * 33], d);
    return d + b2_0;
}

// ---------------------------------------------------------------------------
// Round-based march with wave-level stream compaction.
// round0 != 0: ray i starts fresh (cd = NEAR). Otherwise ray state comes from
// the dense in-queue. Each ray advances up to KCHUNK steps; terminated rays
// write t (and append to the hit queue); survivors are ballot-compacted into
// the out-queue. Waves are therefore always full of LIVE rays, eliminating
// the max-of-64 straggler waste of the monolithic kernel.
// ---------------------------------------------------------------------------
__global__ __launch_bounds__(256, 4)
void march_round(const float* __restrict__ rays,
                 const float* __restrict__ W0, const float* __restrict__ b0,
                 const float* __restrict__ W1, const float* __restrict__ b1,
                 const float* __restrict__ W2, const float* __restrict__ b2,
                 int round0, int it_base,
                 const int* __restrict__ in_cnt,
                 const int* __restrict__ in_idx, const float* __restrict__ in_cd,
                 int* __restrict__ out_cnt,
                 int* __restrict__ out_idx, float* __restrict__ out_cd,
                 float* __restrict__ t_out,
                 int* __restrict__ hitq, int* __restrict__ hit_cnt)
{
    const int i    = blockIdx.x * 256 + threadIdx.x;
    const int lane = threadIdx.x & 63;
    const int n    = round0 ? NRAYS : *in_cnt;

    bool alive = (i < n);
    bool hit   = false;
    int  ridx  = 0;
    float cd   = NEARV;
    int  it    = it_base;

    if (alive) {
        if (round0) {
            ridx = i;
        } else {
            ridx = in_idx[i];
            cd   = in_cd[i];
        }
    }
    if (__ballot(alive) == 0ull) return;   // whole wave empty

    const float* r = rays + (size_t)ridx * 6;   // dead lanes read ray 0 (in-bounds)
    const float ox = r[0], oy = r[1], oz = r[2];
    const float rdx = r[3], rdy = r[4], rdz = r[5];
    const float b2_0 = b2[0];

    for (int s = 0; s < KCHUNK; ++s) {
        if (__ballot(alive) == 0ull) break;

        const float px = ox + rdx * cd;
        const float py = oy + rdy * cd;
        const float pz = oz + rdz * cd;

        const float d = sdf_eval(px, py, pz, W0, b0, W1, b1, W2, b2_0);

        if (alive) {
            ++it;
            if (d < EPSV && cd <= FARV) hit = true;
            cd += d;
            if (hit || cd > FARV || it >= MAXIT) {
                t_out[ridx] = cd;
                if (hit) {
                    const int p = atomicAdd(hit_cnt, 1);
                    hitq[p] = ridx;
                }
                alive = false;
            }
        }
    }

    // Wave-aggregated compaction of survivors into the out-queue.
    const unsigned long long m = __ballot(alive);
    if (m != 0ull) {
        const int leader = __builtin_ctzll(m);
        int base = 0;
        if (lane == leader) base = atomicAdd(out_cnt, __builtin_popcountll(m));
        base = __shfl(base, leader);
        if (alive) {
            const int off = __builtin_popcountll(m & ((1ull << lane) - 1ull));
            out_idx[base + off] = ridx;
            out_cd[base + off]  = cd;
        }
    }
}

// ---------------------------------------------------------------------------
// Shade only the hit rays (dense hit queue). Output was memset to zero, so
// misses need no work. Arithmetic for hit rays is bit-identical to the
// previously passing shade kernel.
// ---------------------------------------------------------------------------
__global__ __launch_bounds__(256, 2)
void shade_hit(const float* __restrict__ rays,
               const float* __restrict__ W0, const float* __restrict__ b0,
               const float* __restrict__ W1, const float* __restrict__ b1,
               const float* __restrict__ W2, const float* __restrict__ b2,
               const float* __restrict__ RW0, const float* __restrict__ Rb0,
               const float* __restrict__ RW1, const float* __restrict__ Rb1,
               const float* __restrict__ t_in,
               const int* __restrict__ hitq, const int* __restrict__ hit_cnt,
               float* __restrict__ out)
{
    const int n = *hit_cnt;
    if (blockIdx.x * 256 >= n) return;   // whole block empty -> skip staging

    __shared__ float sW0[3 * 64];
    __shared__ float sb0[64];
    __shared__ float sW1[64 * 64];
    __shared__ float sb1[64];
    __shared__ float sW2T[33 * 64];   // [c][j] = W2[j][c]
    __shared__ float sb2[33];
    __shared__ float sRW0T[64 * 48];  // [u][f] = RW0[f][u], padded 41->48
    __shared__ float sRb0[64];
    __shared__ float sRW1[64 * 3];
    __shared__ float sRb1[3];

    const int tid = threadIdx.x;
    for (int i = tid; i < 3 * 64; i += 256) sW0[i] = W0[i];
    for (int i = tid; i < 64 * 64; i += 256) sW1[i] = W1[i];
    for (int i = tid; i < 33 * 64; i += 256) {
        const int c = i >> 6, j = i & 63;
        sW2T[i] = W2[j * 33 + c];
    }
    for (int i = tid; i < 64 * 41; i += 256) {
        const int u = i / 41, f = i - u * 41;
        sRW0T[u * 48 + f] = RW0[f * 64 + u];
    }
    if (tid < 64) { sb0[tid] = b0[tid]; sb1[tid] = b1[tid]; sRb0[tid] = Rb0[tid]; }
    if (tid < 33) sb2[tid] = b2[tid];
    if (tid < 192) sRW1[tid] = RW1[tid];
    if (tid < 3) sRb1[tid] = Rb1[tid];
    __syncthreads();

    const int qi = blockIdx.x * 256 + tid;
    if (qi >= n) return;
    const int i = hitq[qi];

    const float* r = rays + (size_t)i * 6;
    const float cd = t_in[i];
    const float ox = r[0], oy = r[1], oz = r[2];
    const float dx = r[3], dy = r[4], dz = r[5];
    const float px = ox + dx * cd;
    const float py = oy + dy * cd;
    const float pz = oz + dz * cd;

    // ---- forward, layer 1 accumulation ----
    float h1[64];
    #pragma unroll
    for (int j = 0; j < 64; ++j) h1[j] = 0.f;

    for (int k = 0; k < 64; ++k) {
        float z = px * sW0[k] + py * sW0[64 + k] + pz * sW0[128 + k];
        z += sb0[k];
        const float a = fmaxf(z, 0.f);
        #pragma unroll
        for (int j = 0; j < 64; ++j) h1[j] = fmaf(a, sW1[k * 64 + j], h1[j]);
    }
    #pragma unroll
    for (int j = 0; j < 64; ++j) h1[j] = fmaxf(h1[j] + sb1[j], 0.f);

    // ---- latent = out[:,1:33] ----
    float lat[32];
    #pragma unroll
    for (int c = 1; c < 33; ++c) {
        float acc = 0.f;
        #pragma unroll
        for (int j = 0; j < 64; ++j) acc = fmaf(h1[j], sW2T[c * 64 + j], acc);
        lat[c - 1] = acc + sb2[c];
    }

    // ---- backward: gz1 = (z1>0) ? W2[:,0] : 0 ----
    #pragma unroll
    for (int j = 0; j < 64; ++j) h1[j] = (h1[j] > 0.f) ? sW2T[j] : 0.f;

    float nx = 0.f, ny = 0.f, nz = 0.f;
    for (int k = 0; k < 64; ++k) {
        float z = px * sW0[k] + py * sW0[64 + k] + pz * sW0[128 + k];
        z += sb0[k];
        float g = 0.f;
        #pragma unroll
        for (int j = 0; j < 64; ++j) g = fmaf(h1[j], sW1[k * 64 + j], g);
        if (z > 0.f) {
            nx = fmaf(g, sW0[k], nx);
            ny = fmaf(g, sW0[64 + k], ny);
            nz = fmaf(g, sW0[128 + k], nz);
        }
    }

    // ---- render MLP: feat(41) = [pts, r_d, nrm, latent] ----
    float r0 = 0.f, r1 = 0.f, r2 = 0.f;
    for (int u = 0; u < 64; ++u) {
        const float* w = &sRW0T[u * 48];
        float a = px * w[0] + py * w[1] + pz * w[2];
        a = fmaf(dx, w[3], a); a = fmaf(dy, w[4], a); a = fmaf(dz, w[5], a);
        a = fmaf(nx, w[6], a); a = fmaf(ny, w[7], a); a = fmaf(nz, w[8], a);
        #pragma unroll
        for (int q = 0; q < 32; ++q) a = fmaf(lat[q], w[9 + q], a);
        a += sRb0[u];
        const float ru = fmaxf(a, 0.f);
        r0 = fmaf(ru, sRW1[u * 3 + 0], r0);
        r1 = fmaf(ru, sRW1[u * 3 + 1], r1);
        r2 = fmaf(ru, sRW1[u * 3 + 2], r2);
    }
    r0 += sRb1[0]; r1 += sRb1[1]; r2 += sRb1[2];

    out[i * 3 + 0] = 1.f / (1.f + expf(-r0));
    out[i * 3 + 1] = 1.f / (1.f + expf(-r1));
    out[i * 3 + 2] = 1.f / (1.f + expf(-r2));
}

// ---------------------------------------------------------------------------
// Fallback path (only if workspace is too small for the queues): the
// previously passing monolithic march + full shade.
// ---------------------------------------------------------------------------
__global__ __launch_bounds__(256, 4)
void march_kernel(const float* __restrict__ rays,
                  const float* __restrict__ W0, const float* __restrict__ b0,
                  const float* __restrict__ W1, const float* __restrict__ b1,
                  const float* __restrict__ W2, const float* __restrict__ b2,
                  float* __restrict__ t_out, int* __restrict__ hit_out,
                  int* __restrict__ counter)
{
    float ox = 0.f, oy = 0.f, oz = 0.f, rdx = 0.f, rdy = 0.f, rdz = 0.f;
    float cd = 0.f;
    int ridx = -1, it = 0;
    bool has = false, hit = false, exhausted = false;

    const float b2_0 = b2[0];

    while (true) {
        if (!has && !exhausted) {
            int idx = atomicAdd(counter, 1);
            if (idx < NRAYS) {
                const float* r = rays + (size_t)idx * 6;
                ox = r[0]; oy = r[1]; oz = r[2];
                rdx = r[3]; rdy = r[4]; rdz = r[5];
                cd = NEARV; it = 0; hit = false; has = true; ridx = idx;
            } else {
                exhausted = true;
            }
        }
        if (__ballot(has) == 0ull) break;

        const float px = ox + rdx * cd;
        const float py = oy + rdy * cd;
        const float pz = oz + rdz * cd;

        const float d = sdf_eval(px, py, pz, W0, b0, W1, b1, W2, b2_0);

        if (has) {
            ++it;
            if (d < EPSV && cd <= FARV) hit = true;
            cd += d;
            if (hit || cd > FARV || it >= MAXIT) {
                t_out[ridx] = cd;
                hit_out[ridx] = hit ? 1 : 0;
                has = false;
            }
        }
    }
}

__global__ __launch_bounds__(256, 2)
void shade_kernel(const float* __restrict__ rays,
                  const float* __restrict__ W0, const float* __restrict__ b0,
                  const float* __restrict__ W1, const float* __restrict__ b1,
                  const float* __restrict__ W2, const float* __restrict__ b2,
                  const float* __restrict__ RW0, const float* __restrict__ Rb0,
                  const float* __restrict__ RW1, const float* __restrict__ Rb1,
                  const float* __restrict__ t_in, const int* __restrict__ hit_in,
                  float* __restrict__ out)
{
    __shared__ float sW0[3 * 64];
    __shared__ float sb0[64];
    __shared__ float sW1[64 * 64];
    __shared__ float sb1[64];
    __shared__ float sW2T[33 * 64];
    __shared__ float sb2[33];
    __shared__ float sRW0T[64 * 48];
    __shared__ float sRb0[64];
    __shared__ float sRW1[64 * 3];
    __shared__ float sRb1[3];

    const int tid = threadIdx.x;
    for (int i = tid; i < 3 * 64; i += 256) sW0[i] = W0[i];
    for (int i = tid; i < 64 * 64; i += 256) sW1[i] = W1[i];
    for (int i = tid; i < 33 * 64; i += 256) {
        const int c = i >> 6, j = i & 63;
        sW2T[i] = W2[j * 33 + c];
    }
    for (int i = tid; i < 64 * 41; i += 256) {
        const int u = i / 41, f = i - u * 41;
        sRW0T[u * 48 + f] = RW0[f * 64 + u];
    }
    if (tid < 64) { sb0[tid] = b0[tid]; sb1[tid] = b1[tid]; sRb0[tid] = Rb0[tid]; }
    if (tid < 33) sb2[tid] = b2[tid];
    if (tid < 192) sRW1[tid] = RW1[tid];
    if (tid < 3) sRb1[tid] = Rb1[tid];
    __syncthreads();

    const int i = blockIdx.x * 256 + tid;
    const bool hit = hit_in[i] != 0;

    if (__ballot(hit) == 0ull) {
        out[i * 3 + 0] = 0.f;
        out[i * 3 + 1] = 0.f;
        out[i * 3 + 2] = 0.f;
        return;
    }

    const float* r = rays + (size_t)i * 6;
    const float cd = t_in[i];
    const float ox = r[0], oy = r[1], oz = r[2];
    const float dx = r[3], dy = r[4], dz = r[5];
    const float px = ox + dx * cd;
    const float py = oy + dy * cd;
    const float pz = oz + dz * cd;

    float h1[64];
    #pragma unroll
    for (int j = 0; j < 64; ++j) h1[j] = 0.f;

    for (int k = 0; k < 64; ++k) {
        float z = px * sW0[k] + py * sW0[64 + k] + pz * sW0[128 + k];
        z += sb0[k];
        const float a = fmaxf(z, 0.f);
        #pragma unroll
        for (int j = 0; j < 64; ++j) h1[j] = fmaf(a, sW1[k * 64 + j], h1[j]);
    }
    #pragma unroll
    for (int j = 0; j < 64; ++j) h1[j] = fmaxf(h1[j] + sb1[j], 0.f);

    float lat[32];
    #pragma unroll
    for (int c = 1; c < 33; ++c) {
        float acc = 0.f;
        #pragma unroll
        for (int j = 0; j < 64; ++j) acc = fmaf(h1[j], sW2T[c * 64 + j], acc);
        lat[c - 1] = acc + sb2[c];
    }

    #pragma unroll
    for (int j = 0; j < 64; ++j) h1[j] = (h1[j] > 0.f) ? sW2T[j] : 0.f;

    float nx = 0.f, ny = 0.f, nz = 0.f;
    for (int k = 0; k < 64; ++k) {
        float z = px * sW0[k] + py * sW0[64 + k] + pz * sW0[128 + k];
        z += sb0[k];
        float g = 0.f;
        #pragma unroll
        for (int j = 0; j < 64; ++j) g = fmaf(h1[j], sW1[k * 64 + j], g);
        if (z > 0.f) {
            nx = fmaf(g, sW0[k], nx);
            ny = fmaf(g, sW0[64 + k], ny);
            nz = fmaf(g, sW0[128 + k], nz);
        }
    }
    if (!hit) { nx = 0.f; ny = 0.f; nz = 0.f; }

    float r0 = 0.f, r1 = 0.f, r2 = 0.f;
    for (int u = 0; u < 64; ++u) {
        const float* w = &sRW0T[u * 48];
        float a = px * w[0] + py * w[1] + pz * w[2];
        a = fmaf(dx, w[3], a); a = fmaf(dy, w[4], a); a = fmaf(dz, w[5], a);
        a = fmaf(nx, w[6], a); a = fmaf(ny, w[7], a); a = fmaf(nz, w[8], a);
        #pragma unroll
        for (int q = 0; q < 32; ++q) a = fmaf(lat[q], w[9 + q], a);
        a += sRb0[u];
        const float ru = fmaxf(a, 0.f);
        r0 = fmaf(ru, sRW1[u * 3 + 0], r0);
        r1 = fmaf(ru, sRW1[u * 3 + 1], r1);
        r2 = fmaf(ru, sRW1[u * 3 + 2], r2);
    }
    r0 += sRb1[0]; r1 += sRb1[1]; r2 += sRb1[2];

    const float o0 = 1.f / (1.f + expf(-r0));
    const float o1 = 1.f / (1.f + expf(-r1));
    const float o2 = 1.f / (1.f + expf(-r2));

    out[i * 3 + 0] = hit ? o0 : 0.f;
    out[i * 3 + 1] = hit ? o1 : 0.f;
    out[i * 3 + 2] = hit ? o2 : 0.f;
}

extern "C" void kernel_launch(void* const* d_in, const int* in_sizes, int n_in,
                              void* d_out, int out_size, void* d_ws, size_t ws_size,
                              hipStream_t stream) {
    const float* rays = (const float*)d_in[0];
    const float* W0   = (const float*)d_in[1];
    const float* b0   = (const float*)d_in[2];
    const float* W1   = (const float*)d_in[3];
    const float* b1   = (const float*)d_in[4];
    const float* W2   = (const float*)d_in[5];
    const float* b2   = (const float*)d_in[6];
    const float* RW0  = (const float*)d_in[7];
    const float* Rb0  = (const float*)d_in[8];
    const float* RW1  = (const float*)d_in[9];
    const float* Rb1  = (const float*)d_in[10];

    // Workspace layout (4-byte units):
    //   [0..15]                     counters: cnt[r]=survivors after round r, cnt[15]=hit count
    //   [16          .. 16+N)      t
    //   [16+N        .. 16+2N)     queue A idx
    //   [16+2N       .. 16+3N)     queue A cd
    //   [16+3N       .. 16+4N)     queue B idx
    //   [16+4N       .. 16+5N)     queue B cd
    //   [16+5N       .. 16+6N)     hit queue
    const size_t need = (size_t)(16 + 6 * NRAYS) * 4;

    if (ws_size >= need) {
        int*   cnt  = (int*)d_ws;
        float* t_ws = (float*)d_ws + 16;
        int*   qiA  = (int*)d_ws + 16 + (size_t)NRAYS;
        float* qcA  = (float*)d_ws + 16 + 2 * (size_t)NRAYS;
        int*   qiB  = (int*)d_ws + 16 + 3 * (size_t)NRAYS;
        float* qcB  = (float*)d_ws + 16 + 4 * (size_t)NRAYS;
        int*   hitq = (int*)d_ws + 16 + 5 * (size_t)NRAYS;

        hipMemsetAsync(cnt, 0, 16 * sizeof(int), stream);
        hipMemsetAsync(d_out, 0, (size_t)out_size, stream);

        // Round 0: all rays fresh, survivors -> queue A (cnt[0]).
        march_round<<<NRAYS / 256, 256, 0, stream>>>(
            rays, W0, b0, W1, b1, W2, b2,
            1, 0, nullptr, nullptr, nullptr,
            &cnt[0], qiA, qcA, t_ws, hitq, &cnt[15]);

        for (int r2 = 1; r2 < NROUNDS; ++r2) {
            const int*   icnt = &cnt[r2 - 1];
            int*         ocnt = &cnt[r2];
            const int*   ii = (r2 & 1) ? qiA : qiB;
            const float* ic = (r2 & 1) ? qcA : qcB;
            int*         oi = (r2 & 1) ? qiB : qiA;
            float*       oc = (r2 & 1) ? qcB : qcA;
            march_round<<<NRAYS / 256, 256, 0, stream>>>(
                rays, W0, b0, W1, b1, W2, b2,
                0, r2 * KCHUNK, icnt, ii, ic,
                ocnt, oi, oc, t_ws, hitq, &cnt[15]);
        }

        shade_hit<<<NRAYS / 256, 256, 0, stream>>>(
            rays, W0, b0, W1, b1, W2, b2, RW0, Rb0, RW1, Rb1,
            t_ws, hitq, &cnt[15], (float*)d_out);
    } else {
        // Fallback: previous passing path.
        float* t_ws  = (float*)d_ws;
        int*   hit_ws = (int*)d_ws + NRAYS;
        int*   ctr    = (int*)d_ws + 2 * NRAYS;

        hipMemsetAsync(ctr, 0, sizeof(int), stream);
        march_kernel<<<1024, 256, 0, stream>>>(rays, W0, b0, W1, b1, W2, b2,
                                               t_ws, hit_ws, ctr);
        shade_kernel<<<NRAYS / 256, 256, 0, stream>>>(rays, W0, b0, W1, b1, W2, b2,
                                                      RW0, Rb0, RW1, Rb1,
                                                      t_ws, hit_ws, (float*)d_out);
    }
}